// Round 5
// baseline (248.401 us; speedup 1.0000x reference)
//
#include <hip/hip_runtime.h>
#include <hip/hip_bf16.h>

#define B_    8
#define N_    1024
#define DIM_  512
#define H_    8
#define DH_   64
#define SCALE_ 0.125f

typedef unsigned short u16;
typedef __attribute__((ext_vector_type(8))) short bf16x8;
typedef __attribute__((ext_vector_type(4))) float f32x4;

__device__ __forceinline__ u16 f2bf(float f) {
  union { float f; unsigned u; } v; v.f = f;
  return (u16)((v.u + 0x7fffu + ((v.u >> 16) & 1u)) >> 16);
}
__device__ __forceinline__ unsigned pack2(float a, float b) {
  return (unsigned)f2bf(a) | ((unsigned)f2bf(b) << 16);
}
__device__ __forceinline__ void cp16(const void* g, void* l) {
  __builtin_amdgcn_global_load_lds(
      (const __attribute__((address_space(1))) unsigned*)g,
      (__attribute__((address_space(3))) unsigned*)l, 16, 0, 0);
}

// ---------------- Kernel 0: fp32 -> bf16 convert (weights only) -------------
__global__ __launch_bounds__(256) void convert_kernel(
    const float* __restrict__ Wq, const float* __restrict__ Wp,
    u16* __restrict__ Wqb, u16* __restrict__ Wpb) {
  const int NQ4 = (3 * DIM_ * DIM_) / 4;   // 196608
  const int i = blockIdx.x * 256 + threadIdx.x;   // grid covers exactly 262144
  const float* s; u16* d; int off;
  if (i < NQ4) { s = Wq; d = Wqb; off = i; }
  else         { s = Wp; d = Wpb; off = i - NQ4; }
  float4 f = *(const float4*)(s + (size_t)off * 4);
  uint2 u; u.x = pack2(f.x, f.y); u.y = pack2(f.z, f.w);
  *(uint2*)(d + (size_t)off * 4) = u;
}

// ------- Kernel 1: QKV GEMM, register-resident A, W-only LDS dbuf -----------
// block: 64 m-rows x 128 j-cols; wave w owns m-rows m0+16w..+15 (all 128 j)
__global__ __launch_bounds__(256) void qkv_gemm(
    const float* __restrict__ X, const u16* __restrict__ Wb,
    u16* __restrict__ Q, u16* __restrict__ K, u16* __restrict__ Vt) {
  __shared__ __align__(16) u16 smem[2 * 128 * 64];   // W dbuf; epilogue transpose
  const int t = threadIdx.x;
  const int wv = t >> 6, lane = t & 63, quad = (lane >> 4) & 3, l15 = lane & 15;
  const int m0 = blockIdx.x * 64;
  const int j0 = blockIdx.y * 128;
  const int srow8 = lane >> 3, schunk = (lane & 7) ^ srow8;

  // A fragments in registers: 16 ks-steps covering K=512
  union { bf16x8 v; unsigned u[4]; } areg[16];
  {
    const float* xp = X + (size_t)(m0 + 16 * wv + l15) * DIM_ + quad * 8;
#pragma unroll
    for (int ks = 0; ks < 16; ks++) {
      float4 f0 = *(const float4*)(xp + ks * 32);
      float4 f1 = *(const float4*)(xp + ks * 32 + 4);
      areg[ks].u[0] = pack2(f0.x, f0.y); areg[ks].u[1] = pack2(f0.z, f0.w);
      areg[ks].u[2] = pack2(f1.x, f1.y); areg[ks].u[3] = pack2(f1.z, f1.w);
    }
  }

  const u16* wrow = Wb + (size_t)(j0 + 32 * wv + srow8) * DIM_ + schunk * 8;

  f32x4 zero = {0.f, 0.f, 0.f, 0.f};
  f32x4 acc[8];
#pragma unroll
  for (int jb = 0; jb < 8; jb++) acc[jb] = zero;

  // prologue: stage kt=0 into buf 0 (128 rows x 64 k = 16 KB)
#pragma unroll
  for (int i = 0; i < 4; i++)
    cp16(wrow + (size_t)(8 * i) * DIM_, &smem[(32 * wv + 8 * i) * 64]);

  for (int kt = 0; kt < 8; kt++) {
    const int cur = kt & 1;
    __syncthreads();   // drains cp16(kt); waves done reading buf cur^1
    if (kt < 7) {
#pragma unroll
      for (int i = 0; i < 4; i++)
        cp16(wrow + (size_t)(8 * i) * DIM_ + (kt + 1) * 64,
             &smem[((cur ^ 1) * 128 + 32 * wv + 8 * i) * 64]);
    }
#pragma unroll
    for (int ks = 0; ks < 2; ks++)
#pragma unroll
      for (int jb = 0; jb < 8; jb++) {
        bf16x8 bfr = *(const bf16x8*)&smem[(cur * 128 + 16 * jb + l15) * 64 +
                                           (((ks << 2) | quad) ^ (l15 & 7)) * 8];
        acc[jb] = __builtin_amdgcn_mfma_f32_16x16x32_bf16(areg[2 * kt + ks].v, bfr,
                                                          acc[jb], 0, 0, 0);
      }
  }

  const int tsel = j0 >> 9;   // 0=Q (scale folded in), 1=K, 2=V
  __syncthreads();
  if (tsel == 2) {
#pragma unroll
    for (int jb = 0; jb < 8; jb++) {
      const int j = j0 + 16 * jb + l15;
      const int h = (j >> 6) & 7, d = j & 63;
      const int mb = m0 + 16 * wv + quad * 4;
      const int b = mb >> 10, n = mb & 1023;
      ushort4 v4;
      v4.x = f2bf(acc[jb][0]); v4.y = f2bf(acc[jb][1]);
      v4.z = f2bf(acc[jb][2]); v4.w = f2bf(acc[jb][3]);
      *(ushort4*)&Vt[((size_t)(b * H_ + h) * DH_ + d) * N_ + n] = v4;
    }
  } else {
    const float qs = (tsel == 0) ? SCALE_ : 1.f;
#pragma unroll
    for (int jb = 0; jb < 8; jb++)
#pragma unroll
      for (int rr = 0; rr < 4; rr++)
        smem[(16 * wv + quad * 4 + rr) * 136 + 16 * jb + l15] = f2bf(acc[jb][rr] * qs);
    __syncthreads();
    const int r = t >> 2, qd = t & 3;
    const int m = m0 + r, b = m >> 10, n = m & 1023;
    const int h = ((j0 >> 6) & 7) + (qd >> 1), d0 = (qd & 1) * 32;
    u16* dst = (tsel == 0 ? Q : K) + ((size_t)(b * H_ + h) * N_ + n) * DH_ + d0;
    const u16* s = &smem[r * 136 + qd * 32];
#pragma unroll
    for (int cc = 0; cc < 2; cc++)
      *(uint4*)&dst[cc * 8] = *(const uint4*)&s[cc * 8];
    *(uint4*)&dst[16] = *(const uint4*)&s[16];
    *(uint4*)&dst[24] = *(const uint4*)&s[24];
  }
}

// ---- Kernel 2: barrier-free flash attention, fragment-direct global loads --
// wave-independent: each wave = 32 queries x all 1024 keys; no __syncthreads
__global__ __launch_bounds__(256, 2) void attn_kernel(
    const u16* __restrict__ Q, const u16* __restrict__ K,
    const u16* __restrict__ Vt, const float* __restrict__ bias,
    u16* __restrict__ AO) {
  __shared__ __align__(16) u16 sP[128 * 64];   // wave-private rows, xor-swizzled
  const int t = threadIdx.x;
  const int wv = t >> 6, lane = t & 63, quad = (lane >> 4) & 3, l15 = lane & 15;
  const int bh = blockIdx.y, b = bh >> 3, h = bh & 7;
  const int n0 = blockIdx.x * 128 + wv * 32;

  const u16* Qb = Q + ((size_t)bh << 10) * DH_;
  const u16* Kb = K + ((size_t)bh << 10) * DH_;
  const u16* Vb = Vt + (((size_t)bh << 6) << 10);
  const float* bp = bias + (((size_t)h << 10) << 10);

  bf16x8 qf[2][2];
#pragma unroll
  for (int g = 0; g < 2; g++)
#pragma unroll
    for (int ks = 0; ks < 2; ks++)
      qf[g][ks] = *(const bf16x8*)&Qb[(size_t)(n0 + g * 16 + l15) * DH_ + ks * 32 + quad * 8];

  f32x4 zero = {0.f, 0.f, 0.f, 0.f};
  f32x4 O[2][4];
#pragma unroll
  for (int g = 0; g < 2; g++)
#pragma unroll
    for (int db = 0; db < 4; db++) O[g][db] = zero;
  float ls[2] = {0.f, 0.f};
  const int prow = wv * 32 + l15;

  for (int kt = 0; kt < 16; kt++) {
    const int m0k = kt << 6;
    // fragment-direct loads (issued together; compiler leaves later ones in flight)
    bf16x8 kf[2][4], vf[2][4];
#pragma unroll
    for (int ks = 0; ks < 2; ks++)
#pragma unroll
      for (int cb = 0; cb < 4; cb++)
        kf[ks][cb] = *(const bf16x8*)&Kb[(size_t)(m0k + cb * 16 + l15) * DH_ + ks * 32 + quad * 8];
#pragma unroll
    for (int ks = 0; ks < 2; ks++)
#pragma unroll
      for (int db = 0; db < 4; db++)
        vf[ks][db] = *(const bf16x8*)&Vb[(size_t)(db * 16 + l15) * N_ + m0k + ks * 32 + quad * 8];
    float4 bs[2][4];
#pragma unroll
    for (int g = 0; g < 2; g++)
#pragma unroll
      for (int cb = 0; cb < 4; cb++)
        bs[g][cb] = *(const float4*)&bp[(size_t)(n0 + g * 16 + l15) * N_ + m0k + cb * 16 + quad * 4];

    // S^T = K . Q^T  (scale pre-folded into Q)
    f32x4 S[2][4];
#pragma unroll
    for (int g = 0; g < 2; g++)
#pragma unroll
      for (int cb = 0; cb < 4; cb++) S[g][cb] = zero;
#pragma unroll
    for (int ks = 0; ks < 2; ks++)
#pragma unroll
      for (int cb = 0; cb < 4; cb++)
#pragma unroll
        for (int g = 0; g < 2; g++)
          S[g][cb] = __builtin_amdgcn_mfma_f32_16x16x32_bf16(kf[ks][cb], qf[g][ks], S[g][cb], 0, 0, 0);

    // flat-exp softmax (scores bounded ~12; fp32 exp safe), pack P^T into sP
#pragma unroll
    for (int g = 0; g < 2; g++)
#pragma unroll
      for (int cb = 0; cb < 4; cb++) {
        const float p0 = __expf(S[g][cb][0] + bs[g][cb].x);
        const float p1 = __expf(S[g][cb][1] + bs[g][cb].y);
        const float p2 = __expf(S[g][cb][2] + bs[g][cb].z);
        const float p3 = __expf(S[g][cb][3] + bs[g][cb].w);
        ls[g] += (p0 + p1) + (p2 + p3);
        uint2 pk; pk.x = pack2(p0, p1); pk.y = pack2(p2, p3);
        *(uint2*)&sP[(prow + g * 16) * 64 +
                     ((((cb << 1) | (quad >> 1)) ^ (l15 & 7)) << 3) + ((quad & 1) << 2)] = pk;
      }
    asm volatile("s_waitcnt lgkmcnt(0)" ::: "memory");

    // O^T += V^T . P^T
#pragma unroll
    for (int ks = 0; ks < 2; ks++) {
      bf16x8 pf0 = *(const bf16x8*)&sP[prow * 64 + ((((ks << 2) | quad) ^ (l15 & 7)) << 3)];
      bf16x8 pf1 = *(const bf16x8*)&sP[(prow + 16) * 64 + ((((ks << 2) | quad) ^ (l15 & 7)) << 3)];
#pragma unroll
      for (int db = 0; db < 4; db++) {
        O[0][db] = __builtin_amdgcn_mfma_f32_16x16x32_bf16(vf[ks][db], pf0, O[0][db], 0, 0, 0);
        O[1][db] = __builtin_amdgcn_mfma_f32_16x16x32_bf16(vf[ks][db], pf1, O[1][db], 0, 0, 0);
      }
    }
  }

#pragma unroll
  for (int g = 0; g < 2; g++) {
    float l = ls[g];
    l += __shfl_xor(l, 16);
    l += __shfl_xor(l, 32);
    const float inv = 1.f / l;
    const int qg = n0 + g * 16 + l15;
#pragma unroll
    for (int db = 0; db < 4; db++) {
      ushort4 o4;
      o4.x = f2bf(O[g][db][0] * inv); o4.y = f2bf(O[g][db][1] * inv);
      o4.z = f2bf(O[g][db][2] * inv); o4.w = f2bf(O[g][db][3] * inv);
      *(ushort4*)&AO[((size_t)(b << 10) + qg) * DIM_ + h * DH_ + db * 16 + quad * 4] = o4;
    }
  }
}

// ------- Kernel 3: output projection, register-resident A, W LDS dbuf -------
__global__ __launch_bounds__(256) void proj_gemm(
    const u16* __restrict__ Ab, const u16* __restrict__ Wb,
    const float* __restrict__ Pb, float* __restrict__ Out) {
  __shared__ __align__(16) u16 smem[2 * 64 * 64];   // 16 KB W dbuf
  const int t = threadIdx.x;
  const int wv = t >> 6, lane = t & 63, quad = (lane >> 4) & 3, l15 = lane & 15;
  const int m0 = blockIdx.x * 64;
  const int j0 = blockIdx.y * 64;
  const int srow8 = lane >> 3, schunk = (lane & 7) ^ srow8;

  bf16x8 areg[16];
  {
    const u16* ap = Ab + (size_t)(m0 + 16 * wv + l15) * DIM_ + quad * 8;
#pragma unroll
    for (int ks = 0; ks < 16; ks++)
      areg[ks] = *(const bf16x8*)(ap + ks * 32);
  }

  const u16* wrow = Wb + (size_t)(j0 + 16 * wv + srow8) * DIM_ + schunk * 8;

  f32x4 zero = {0.f, 0.f, 0.f, 0.f};
  f32x4 acc[4];
#pragma unroll
  for (int jb = 0; jb < 4; jb++) acc[jb] = zero;

#pragma unroll
  for (int i = 0; i < 2; i++)
    cp16(wrow + (size_t)(8 * i) * DIM_, &smem[(16 * wv + 8 * i) * 64]);

  for (int kt = 0; kt < 8; kt++) {
    const int cur = kt & 1;
    __syncthreads();
    if (kt < 7) {
#pragma unroll
      for (int i = 0; i < 2; i++)
        cp16(wrow + (size_t)(8 * i) * DIM_ + (kt + 1) * 64,
             &smem[((cur ^ 1) * 64 + 16 * wv + 8 * i) * 64]);
    }
#pragma unroll
    for (int ks = 0; ks < 2; ks++)
#pragma unroll
      for (int jb = 0; jb < 4; jb++) {
        bf16x8 bfr = *(const bf16x8*)&smem[(cur * 64 + 16 * jb + l15) * 64 +
                                           (((ks << 2) | quad) ^ (l15 & 7)) * 8];
        acc[jb] = __builtin_amdgcn_mfma_f32_16x16x32_bf16(areg[2 * kt + ks], bfr,
                                                          acc[jb], 0, 0, 0);
      }
  }

#pragma unroll
  for (int jb = 0; jb < 4; jb++) {
    const int jg = j0 + 16 * jb + l15;
    const float pb = Pb[jg];
    const int mb = m0 + 16 * wv + quad * 4;
#pragma unroll
    for (int rr = 0; rr < 4; rr++)
      Out[(size_t)(mb + rr) * DIM_ + jg] = acc[jb][rr] + pb;
  }
}

extern "C" void kernel_launch(void* const* d_in, const int* in_sizes, int n_in,
                              void* d_out, int out_size, void* d_ws, size_t ws_size,
                              hipStream_t stream) {
  const float* x      = (const float*)d_in[0];
  const float* rpe    = (const float*)d_in[1];
  const float* qkv_w  = (const float*)d_in[2];
  const float* proj_w = (const float*)d_in[3];
  const float* proj_b = (const float*)d_in[4];
  float* out = (float*)d_out;

  const size_t perbuf = (size_t)B_ * N_ * DIM_;   // 4,194,304 elems
  u16* Q   = (u16*)d_ws;
  u16* K   = Q + perbuf;
  u16* Vt  = K + perbuf;
  u16* AO  = Vt + perbuf;
  u16* Wqb = AO + perbuf;
  u16* Wpb = Wqb + (size_t)3 * DIM_ * DIM_;

  convert_kernel<<<1024, 256, 0, stream>>>(qkv_w, proj_w, Wqb, Wpb);
  qkv_gemm<<<dim3(128, 12), 256, 0, stream>>>(x, Wqb, Q, K, Vt);
  attn_kernel<<<dim3(8, 64), 256, 0, stream>>>(Q, K, Vt, rpe, AO);
  proj_gemm<<<dim3(128, 8), 256, 0, stream>>>(AO, Wpb, proj_b, out);
}

// Round 6
// 189.400 us; speedup vs baseline: 1.3115x; 1.3115x over previous
//
#include <hip/hip_runtime.h>
#include <hip/hip_bf16.h>

#define B_    8
#define N_    1024
#define DIM_  512
#define H_    8
#define DH_   64
#define SCALE_ 0.125f

typedef unsigned short u16;
typedef __attribute__((ext_vector_type(8))) short bf16x8;
typedef __attribute__((ext_vector_type(4))) float f32x4;
typedef __attribute__((ext_vector_type(4))) _Float16 h16x4;

__device__ __forceinline__ u16 f2bf(float f) {
  union { float f; unsigned u; } v; v.f = f;
  return (u16)((v.u + 0x7fffu + ((v.u >> 16) & 1u)) >> 16);
}
__device__ __forceinline__ unsigned pack2(float a, float b) {
  return (unsigned)f2bf(a) | ((unsigned)f2bf(b) << 16);
}
__device__ __forceinline__ void cp16(const void* g, void* l) {
  __builtin_amdgcn_global_load_lds(
      (const __attribute__((address_space(1))) unsigned*)g,
      (__attribute__((address_space(3))) unsigned*)l, 16, 0, 0);
}

// -------- Kernel 0: convert X/Wq/Wp -> bf16, EB = exp(rpe) -> fp16 ----------
__global__ __launch_bounds__(256) void convert_kernel(
    const float* __restrict__ X, const float* __restrict__ Wq,
    const float* __restrict__ Wp, const float* __restrict__ Bias,
    u16* __restrict__ Xb, u16* __restrict__ Wqb, u16* __restrict__ Wpb,
    _Float16* __restrict__ EB) {
  const int NX4 = (B_ * N_ * DIM_) / 4;        // 1048576
  const int NQ4 = (3 * DIM_ * DIM_) / 4;       // 196608
  const int NP4 = (DIM_ * DIM_) / 4;           // 65536
  // NB4 = 2097152; total = 3407872 = 13312 * 256 (exact grid)
  const int i = blockIdx.x * 256 + threadIdx.x;
  if (i < NX4 + NQ4 + NP4) {
    const float* s; u16* d; int off;
    if (i < NX4)            { s = X;  d = Xb;  off = i; }
    else if (i < NX4 + NQ4) { s = Wq; d = Wqb; off = i - NX4; }
    else                    { s = Wp; d = Wpb; off = i - NX4 - NQ4; }
    float4 f = *(const float4*)(s + (size_t)off * 4);
    uint2 u; u.x = pack2(f.x, f.y); u.y = pack2(f.z, f.w);
    *(uint2*)(d + (size_t)off * 4) = u;
  } else {
    const int off = i - NX4 - NQ4 - NP4;
    float4 f = *(const float4*)(Bias + (size_t)off * 4);
    h16x4 o;
    o[0] = (_Float16)__expf(f.x); o[1] = (_Float16)__expf(f.y);
    o[2] = (_Float16)__expf(f.z); o[3] = (_Float16)__expf(f.w);
    *(h16x4*)(EB + (size_t)off * 4) = o;
  }
}

// ---------------- Kernel 1: QKV GEMM 128x128 tile (scale folded in Q) -------
__global__ __launch_bounds__(256) void qkv_gemm(
    const u16* __restrict__ Ab, const u16* __restrict__ Bb,
    u16* __restrict__ Q, u16* __restrict__ K, u16* __restrict__ Vt) {
  __shared__ __align__(16) u16 smem[128 * 136];   // main: sA/sB; epi: transpose
  u16* sA = smem;
  u16* sB = smem + 128 * 64;
  const int t = threadIdx.x;
  const int wv = t >> 6, lane = t & 63, quad = (lane >> 4) & 3, l15 = lane & 15;
  const int wr = wv >> 1, wc = wv & 1;
  const int m0 = blockIdx.y * 128;
  const int n0 = blockIdx.x * 128;

  const int srow = lane >> 3;
  const int schunk = (lane & 7) ^ srow;
  const size_t ga = (size_t)(m0 + srow) * DIM_ + schunk * 8;
  const size_t gb = (size_t)(n0 + srow) * DIM_ + schunk * 8;

  f32x4 zero = {0.f, 0.f, 0.f, 0.f};
  f32x4 acc[4][4];
#pragma unroll
  for (int i = 0; i < 4; i++)
#pragma unroll
    for (int j = 0; j < 4; j++) acc[i][j] = zero;

  for (int k0 = 0; k0 < DIM_; k0 += 64) {
    __syncthreads();
#pragma unroll
    for (int i = 0; i < 4; i++) {
      const int rb = 32 * wv + 8 * i;
      cp16(Ab + ga + (size_t)rb * DIM_ + k0, &sA[rb * 64]);
      cp16(Bb + gb + (size_t)rb * DIM_ + k0, &sB[rb * 64]);
    }
    __syncthreads();
#pragma unroll
    for (int ks = 0; ks < 2; ks++) {
      bf16x8 af[4], bfv[4];
#pragma unroll
      for (int i = 0; i < 4; i++)
        af[i] = *(const bf16x8*)&sA[(wr * 64 + 16 * i + l15) * 64 +
                                    (((ks << 2) | quad) ^ (l15 & 7)) * 8];
#pragma unroll
      for (int j = 0; j < 4; j++)
        bfv[j] = *(const bf16x8*)&sB[(wc * 64 + 16 * j + l15) * 64 +
                                     (((ks << 2) | quad) ^ (l15 & 7)) * 8];
#pragma unroll
      for (int i = 0; i < 4; i++)
#pragma unroll
        for (int j = 0; j < 4; j++)
          acc[i][j] = __builtin_amdgcn_mfma_f32_16x16x32_bf16(af[i], bfv[j], acc[i][j], 0, 0, 0);
    }
  }

  const int tsel = n0 >> 9;   // 0=Q,1=K,2=V
  __syncthreads();
  if (tsel == 2) {
#pragma unroll
    for (int j = 0; j < 4; j++) {
      const int jg = n0 + wc * 64 + 16 * j + l15;
      const int h = (jg >> 6) & 7, d = jg & 63;
#pragma unroll
      for (int i = 0; i < 4; i++) {
        const int mbase = m0 + wr * 64 + 16 * i + quad * 4;
        const int b = mbase >> 10, nb = mbase & 1023;
        ushort4 v4;
        v4.x = f2bf(acc[i][j][0]); v4.y = f2bf(acc[i][j][1]);
        v4.z = f2bf(acc[i][j][2]); v4.w = f2bf(acc[i][j][3]);
        *(ushort4*)&Vt[(((size_t)(b * H_ + h)) * DH_ + d) * N_ + nb] = v4;
      }
    }
  } else {
    const float qs = (tsel == 0) ? SCALE_ : 1.f;   // fold softmax scale into Q
#pragma unroll
    for (int j = 0; j < 4; j++)
#pragma unroll
      for (int i = 0; i < 4; i++)
#pragma unroll
        for (int rr = 0; rr < 4; rr++)
          smem[(wr * 64 + 16 * i + quad * 4 + rr) * 136 + wc * 64 + 16 * j + l15] =
              f2bf(acc[i][j][rr] * qs);
    __syncthreads();
    const int row = t & 127, half = t >> 7;
    const int m = m0 + row;
    const int b = m >> 10, n = m & 1023;
    const int jg0 = n0 + half * 64;
    const int h = (jg0 >> 6) & 7;
    u16* dst = (tsel == 0 ? Q : K) + (((size_t)(b * H_ + h)) * N_ + n) * DH_;
    const u16* srw = &smem[row * 136 + half * 64];
#pragma unroll
    for (int cc = 0; cc < 8; cc++)
      *(uint4*)&dst[cc * 8] = *(const uint4*)&srw[cc * 8];
  }
}

// -- Kernel 2: flash attn, S^T + EB-multiply flat-exp + pipelined staging ----
// R2 structure (4 waves, VGPR-roundtrip staging, 2 barriers/tile) with:
// 32 KB swizzled LDS (5 blocks/CU), fp16 EB, K/V global loads prefetched 1 tile ahead
__global__ __launch_bounds__(256) void attn_kernel(
    const u16* __restrict__ Q, const u16* __restrict__ K,
    const u16* __restrict__ Vt, const _Float16* __restrict__ EB,
    u16* __restrict__ AO) {
  __shared__ __align__(16) u16 sQ[64 * 64];
  __shared__ __align__(16) u16 sK[64 * 64];
  __shared__ __align__(16) u16 sV[64 * 64];
  __shared__ __align__(16) u16 sP[64 * 64];
  const int t = threadIdx.x;
  const int wv = t >> 6, lane = t & 63, quad = (lane >> 4) & 3, l15 = lane & 15;
  const int n0 = blockIdx.x << 6;
  const int bh = blockIdx.y, b = bh >> 3, h = bh & 7;
  const int r = t >> 2, cc = t & 3, r7 = r & 7;
  const int slot0 = (((cc << 1)) ^ r7) << 3;
  const int slot1 = (((cc << 1) | 1) ^ r7) << 3;

  const u16* Qb = Q + ((size_t)bh << 10) * DH_;
  const u16* Kb = K + ((size_t)bh << 10) * DH_;
  const u16* Vb = Vt + ((size_t)bh << 6) * N_;

  { // stage Q once (swizzled)
    const u16* src = Qb + (size_t)(n0 + r) * DH_ + cc * 16;
    uint4 a = *(const uint4*)src, b4 = *(const uint4*)(src + 8);
    *(uint4*)&sQ[r * 64 + slot0] = a;
    *(uint4*)&sQ[r * 64 + slot1] = b4;
  }
  // prefetch K/V tile 0 into registers
  uint4 kra = *(const uint4*)(Kb + (size_t)r * DH_ + cc * 16);
  uint4 krb = *(const uint4*)(Kb + (size_t)r * DH_ + cc * 16 + 8);
  uint4 vra = *(const uint4*)(Vb + (size_t)r * N_ + cc * 16);
  uint4 vrb = *(const uint4*)(Vb + (size_t)r * N_ + cc * 16 + 8);

  const int qg = n0 + 16 * wv + l15;
  const _Float16* ebp = EB + ((size_t)h * N_ + qg) * N_ + quad * 4;
  h16x4 ebc[4], ebn[4];
#pragma unroll
  for (int cb = 0; cb < 4; cb++) ebc[cb] = *(const h16x4*)(ebp + 16 * cb);

  f32x4 zero = {0.f, 0.f, 0.f, 0.f};
  f32x4 O[4];
  O[0] = zero; O[1] = zero; O[2] = zero; O[3] = zero;
  float lsum = 0.f;

  for (int kt = 0; kt < 16; kt++) {
    __syncthreads();   // all waves done reading previous tile
    *(uint4*)&sK[r * 64 + slot0] = kra;
    *(uint4*)&sK[r * 64 + slot1] = krb;
    *(uint4*)&sV[r * 64 + slot0] = vra;
    *(uint4*)&sV[r * 64 + slot1] = vrb;
    // issue next tile's global loads now; they fly during this tile's compute
    if (kt < 15) {
      const int m1 = (kt + 1) << 6;
      kra = *(const uint4*)(Kb + (size_t)(m1 + r) * DH_ + cc * 16);
      krb = *(const uint4*)(Kb + (size_t)(m1 + r) * DH_ + cc * 16 + 8);
      vra = *(const uint4*)(Vb + (size_t)r * N_ + m1 + cc * 16);
      vrb = *(const uint4*)(Vb + (size_t)r * N_ + m1 + cc * 16 + 8);
    }
    const int mn = (kt < 15) ? ((kt + 1) << 6) : 0;
#pragma unroll
    for (int cb = 0; cb < 4; cb++) ebn[cb] = *(const h16x4*)(ebp + mn + 16 * cb);
    __syncthreads();   // staged K/V visible

    // S^T[key][q] = K . Q^T   (scale pre-folded into Q)
    f32x4 S[4];
    S[0] = zero; S[1] = zero; S[2] = zero; S[3] = zero;
#pragma unroll
    for (int ks = 0; ks < 2; ks++) {
      bf16x8 qf = *(const bf16x8*)&sQ[(16 * wv + l15) * 64 +
                                      ((((ks << 2) | quad) ^ (l15 & 7)) << 3)];
#pragma unroll
      for (int cb = 0; cb < 4; cb++) {
        bf16x8 kf = *(const bf16x8*)&sK[(16 * cb + l15) * 64 +
                                        ((((ks << 2) | quad) ^ (l15 & 7)) << 3)];
        S[cb] = __builtin_amdgcn_mfma_f32_16x16x32_bf16(kf, qf, S[cb], 0, 0, 0);
      }
    }

    // p = exp(S) * EB  (flat softmax: scores bounded, fp32 exp safe)
#pragma unroll
    for (int cb = 0; cb < 4; cb++) {
      const float p0 = __expf(S[cb][0]) * (float)ebc[cb][0];
      const float p1 = __expf(S[cb][1]) * (float)ebc[cb][1];
      const float p2 = __expf(S[cb][2]) * (float)ebc[cb][2];
      const float p3 = __expf(S[cb][3]) * (float)ebc[cb][3];
      lsum += (p0 + p1) + (p2 + p3);
      uint2 pk; pk.x = pack2(p0, p1); pk.y = pack2(p2, p3);
      *(uint2*)&sP[(16 * wv + l15) * 64 +
                   ((((cb << 1) | (quad >> 1)) ^ (l15 & 7)) << 3) + ((quad & 1) << 2)] = pk;
    }
    asm volatile("s_waitcnt lgkmcnt(0)" ::: "memory");   // wave-local sP fence

    // O^T[d][q] += V^T . P^T
#pragma unroll
    for (int ks = 0; ks < 2; ks++) {
      bf16x8 pf = *(const bf16x8*)&sP[(16 * wv + l15) * 64 +
                                      ((((ks << 2) | quad) ^ (l15 & 7)) << 3)];
#pragma unroll
      for (int db = 0; db < 4; db++) {
        bf16x8 vf = *(const bf16x8*)&sV[(16 * db + l15) * 64 +
                                        ((((ks << 2) | quad) ^ (l15 & 7)) << 3)];
        O[db] = __builtin_amdgcn_mfma_f32_16x16x32_bf16(vf, pf, O[db], 0, 0, 0);
      }
    }
#pragma unroll
    for (int cb = 0; cb < 4; cb++) ebc[cb] = ebn[cb];
  }

  lsum += __shfl_xor(lsum, 16);
  lsum += __shfl_xor(lsum, 32);
  const float inv = 1.f / lsum;
#pragma unroll
  for (int db = 0; db < 4; db++) {
    ushort4 o4;
    o4.x = f2bf(O[db][0] * inv); o4.y = f2bf(O[db][1] * inv);
    o4.z = f2bf(O[db][2] * inv); o4.w = f2bf(O[db][3] * inv);
    *(ushort4*)&AO[(((size_t)b << 10) + qg) * DIM_ + h * DH_ + 16 * db + (quad << 2)] = o4;
  }
}

// ---------------- Kernel 3: output projection 128x128 tile ------------------
__global__ __launch_bounds__(256) void proj_gemm(
    const u16* __restrict__ Ab, const u16* __restrict__ Bb,
    const float* __restrict__ Pb, float* __restrict__ Out) {
  __shared__ __align__(16) u16 sA[128 * 64];
  __shared__ __align__(16) u16 sB[128 * 64];
  const int t = threadIdx.x;
  const int wv = t >> 6, lane = t & 63, quad = (lane >> 4) & 3, l15 = lane & 15;
  const int wr = wv >> 1, wc = wv & 1;
  const int m0 = blockIdx.y * 128;
  const int n0 = blockIdx.x * 128;

  const int srow = lane >> 3;
  const int schunk = (lane & 7) ^ srow;
  const size_t ga = (size_t)(m0 + srow) * DIM_ + schunk * 8;
  const size_t gb = (size_t)(n0 + srow) * DIM_ + schunk * 8;

  f32x4 zero = {0.f, 0.f, 0.f, 0.f};
  f32x4 acc[4][4];
#pragma unroll
  for (int i = 0; i < 4; i++)
#pragma unroll
    for (int j = 0; j < 4; j++) acc[i][j] = zero;

  for (int k0 = 0; k0 < DIM_; k0 += 64) {
    __syncthreads();
#pragma unroll
    for (int i = 0; i < 4; i++) {
      const int rb = 32 * wv + 8 * i;
      cp16(Ab + ga + (size_t)rb * DIM_ + k0, &sA[rb * 64]);
      cp16(Bb + gb + (size_t)rb * DIM_ + k0, &sB[rb * 64]);
    }
    __syncthreads();
#pragma unroll
    for (int ks = 0; ks < 2; ks++) {
      bf16x8 af[4], bfv[4];
#pragma unroll
      for (int i = 0; i < 4; i++)
        af[i] = *(const bf16x8*)&sA[(wr * 64 + 16 * i + l15) * 64 +
                                    (((ks << 2) | quad) ^ (l15 & 7)) * 8];
#pragma unroll
      for (int j = 0; j < 4; j++)
        bfv[j] = *(const bf16x8*)&sB[(wc * 64 + 16 * j + l15) * 64 +
                                     (((ks << 2) | quad) ^ (l15 & 7)) * 8];
#pragma unroll
      for (int i = 0; i < 4; i++)
#pragma unroll
        for (int j = 0; j < 4; j++)
          acc[i][j] = __builtin_amdgcn_mfma_f32_16x16x32_bf16(af[i], bfv[j], acc[i][j], 0, 0, 0);
    }
  }

#pragma unroll
  for (int j = 0; j < 4; j++) {
    const int jg = n0 + wc * 64 + 16 * j + l15;
    const float pb = Pb[jg];
#pragma unroll
    for (int i = 0; i < 4; i++) {
      const int mbase = m0 + wr * 64 + 16 * i + quad * 4;
#pragma unroll
      for (int rr = 0; rr < 4; rr++)
        Out[(size_t)(mbase + rr) * DIM_ + jg] = acc[i][j][rr] + pb;
    }
  }
}

extern "C" void kernel_launch(void* const* d_in, const int* in_sizes, int n_in,
                              void* d_out, int out_size, void* d_ws, size_t ws_size,
                              hipStream_t stream) {
  const float* x      = (const float*)d_in[0];
  const float* rpe    = (const float*)d_in[1];
  const float* qkv_w  = (const float*)d_in[2];
  const float* proj_w = (const float*)d_in[3];
  const float* proj_b = (const float*)d_in[4];
  float* out = (float*)d_out;

  const size_t perbuf = (size_t)B_ * N_ * DIM_;   // 4,194,304 elems
  u16* Xb  = (u16*)d_ws;                          // aliased with AO
  u16* Q   = Xb + perbuf;
  u16* K   = Q + perbuf;
  u16* Vt  = K + perbuf;
  u16* Wqb = Vt + perbuf;
  u16* Wpb = Wqb + (size_t)3 * DIM_ * DIM_;
  _Float16* EB = (_Float16*)(Wpb + (size_t)DIM_ * DIM_);  // 16.8 MB fp16
  u16* AO  = Xb;   // lifetimes disjoint

  convert_kernel<<<13312, 256, 0, stream>>>(x, qkv_w, proj_w, rpe, Xb, Wqb, Wpb, EB);
  qkv_gemm<<<dim3(12, 64), 256, 0, stream>>>(Xb, Wqb, Q, K, Vt);
  attn_kernel<<<dim3(16, 64), 256, 0, stream>>>(Q, K, Vt, EB, AO);
  proj_gemm<<<dim3(4, 64), 256, 0, stream>>>(AO, Wpb, proj_b, out);
}